// Round 14
// baseline (1002.704 us; speedup 1.0000x reference)
//
#include <hip/hip_runtime.h>

// CapsNet dynamic routing — fp32 in / fp32 out (verified R11/R12).
// R13 lesson: cooperative fusion regressed 2.2x (grid.sync = cross-XCD L2
// flush + straggler serialization). Back to 6 dispatches; this round removes
// ALL barriers/LDS from the pass inner loop via thread<->(o,b) remap:
//   lane = o (64 o's per wave), wave = one b. logit <u,v> thread-local,
//   softmax denom = 6x shfl_xor, c-store lane-coalesced.
// B=64, Ni=1152, Di=8, No=64, Do=16.
// u[b,i,o,d] = sum_k W[i*8192 + o*128 + d*8 + k] * x[b*9216 + i*8 + k]
// it0: c=1/64       -> s0 -> v0
// it1: l=<u,v0>     -> c1 -> s1 -> v1
// it2: l=<u,v0+v1>  -> c2 (OUT [B,Ni,No]) -> s2 -> v2 (OUT [B,No,Do])

#define B_      64
#define NI_     1152
#define DI_     8
#define NO_     64
#define DO_     16
#define NOD_    1024
#define CH_     96
#define CI_     12
#define BG_     4      // b per block (1 per wave)
#define BSPLIT_ 16     // B_/BG_
#define V_ELEMS 65536

static_assert(CH_ * CI_ == NI_, "chunking");
static_assert(BG_ * BSPLIT_ == B_, "b split");

// MODE 0: c=1/64 (applied in squash), acc sum_i u      -> part
// MODE 1: l=<u,v0>, softmax over o, acc c*u            -> part
// MODE 2: l=<u,v0+v1>, softmax, write c (fp32), acc c*u -> part
template <int MODE>
__global__ __launch_bounds__(256, 4)
void caps_pass(const float* __restrict__ X,
               const float* __restrict__ W,
               const float* __restrict__ vin,
               float* __restrict__ part,
               float* __restrict__ rw)
{
    __shared__ float x_lds[BG_][CI_ * DI_];   // 1.5 KB only

    const int t  = threadIdx.x;
    const int w  = t >> 6;               // wave = local b index
    const int o  = t & 63;               // lane = output capsule
    const int ch = blockIdx.x;           // 0..95 (same-ch blocks 96 apart -> same XCD)
    const int b0 = blockIdx.y * BG_;
    const int i0 = ch * CI_;
    const int b  = b0 + w;

    // stage x[b0..b0+3][i0..i0+11][0..7]: 96 float4
    for (int f = t; f < BG_ * CI_ * DI_ / 4; f += 256) {
        int bb = f / (CI_ * DI_ / 4), r = f - bb * (CI_ * DI_ / 4);
        ((float4*)x_lds)[f] =
            ((const float4*)(X + ((size_t)(b0 + bb) * NI_ + i0) * DI_))[r];
    }
    __syncthreads();   // the ONLY barrier in this kernel

    // per-phase routing vector v[b][o][0..15] -> registers
    float vreg[16];
    if (MODE >= 1) {
        const float4* vg = (const float4*)(vin + (size_t)b * NOD_ + o * 16);
#pragma unroll
        for (int j = 0; j < 4; ++j) {
            float4 q = vg[j];
            vreg[4*j+0] = q.x; vreg[4*j+1] = q.y; vreg[4*j+2] = q.z; vreg[4*j+3] = q.w;
        }
    }

    float acc[16];
#pragma unroll
    for (int d = 0; d < 16; ++d) acc[d] = 0.f;

    const float4* Wq = (const float4*)W;

    for (int ci = 0; ci < CI_; ++ci) {
        const int i = i0 + ci;
        // x[i][0..7] broadcast from LDS (same addr across lanes: conflict-free)
        const float* xb = &x_lds[w][ci * DI_];
        const float x0 = xb[0], x1 = xb[1], x2 = xb[2], x3 = xb[3];
        const float x4 = xb[4], x5 = xb[5], x6 = xb[6], x7 = xb[7];

        // u[d] = W[i][o][d][:] . x[i][:]   — 8 dwordx4 per thread, full-line use
        const float4* wp = Wq + (size_t)i * 2048 + (size_t)o * 32;
        float u[16];
#pragma unroll
        for (int d = 0; d < 16; ++d) {
            float4 q0 = wp[2*d], q1 = wp[2*d + 1];
            float s = q0.x * x0;
            s = fmaf(q0.y, x1, s); s = fmaf(q0.z, x2, s); s = fmaf(q0.w, x3, s);
            s = fmaf(q1.x, x4, s); s = fmaf(q1.y, x5, s);
            s = fmaf(q1.z, x6, s); s = fmaf(q1.w, x7, s);
            u[d] = s;
        }

        if (MODE == 0) {
#pragma unroll
            for (int d = 0; d < 16; ++d) acc[d] += u[d];   // c=1/64 applied in squash
        } else {
            float l = 0.f;                                 // <u, vprev>: thread-local
#pragma unroll
            for (int d = 0; d < 16; ++d) l = fmaf(u[d], vreg[d], l);
            const float e = __expf(l);
            float s = e;                                   // sum over all 64 o (wave)
            s += __shfl_xor(s, 1);  s += __shfl_xor(s, 2);  s += __shfl_xor(s, 4);
            s += __shfl_xor(s, 8);  s += __shfl_xor(s, 16); s += __shfl_xor(s, 32);
            const float c = e / s;
#pragma unroll
            for (int d = 0; d < 16; ++d) acc[d] = fmaf(c, u[d], acc[d]);
            if (MODE == 2)
                rw[((size_t)b * NI_ + i) * NO_ + o] = c;   // lane-coalesced store
        }
    }

    // partial s for this chunk: part[b][ch][o*16 + d]
    float4* pp = (float4*)(part + ((size_t)b * CH_ + ch) * NOD_ + o * 16);
#pragma unroll
    for (int j = 0; j < 4; ++j) {
        float4 val;
        val.x = acc[4*j+0]; val.y = acc[4*j+1]; val.z = acc[4*j+2]; val.w = acc[4*j+3];
        pp[j] = val;
    }
}

// Reduce partials over CH_ chunks, squash over d (16 lanes), emit v.
// MODE 0: s*=1/64, write v0 | MODE 1: write w01=v0+squash(s1) | MODE 2: v2 -> d_out
template <int MODE>
__global__ __launch_bounds__(256)
void caps_squash(const float* __restrict__ part, const float* __restrict__ v0in,
                 float* __restrict__ vout, int nch)
{
    const int col = blockIdx.x * 256 + threadIdx.x;   // b*1024 + o*16 + d
    const int b = col >> 10, od = col & 1023;
    const float* p = part + (size_t)b * nch * NOD_ + od;
    float s = 0.f;
    for (int ch = 0; ch < nch; ++ch) s += p[(size_t)ch * NOD_];
    if (MODE == 0) s *= (1.0f / 64.0f);
    float s2 = s * s;
    s2 += __shfl_xor(s2, 1); s2 += __shfl_xor(s2, 2);
    s2 += __shfl_xor(s2, 4); s2 += __shfl_xor(s2, 8);
    const float scale = s2 / ((1.0f + s2) * sqrtf(s2 + 1e-7f));
    const float v = scale * s;
    if (MODE == 1) vout[col] = v0in[col] + v;
    else           vout[col] = v;
}

// Safety fallback (R11's passing kernel) — only if ws is unexpectedly tiny.
__global__ __launch_bounds__(1024, 1)
void caps_naive(const float* __restrict__ X, const float* __restrict__ W,
                float* __restrict__ outv, float* __restrict__ outc)
{
    __shared__ float xs[NI_ * DI_];
    __shared__ float agree[NO_];
    __shared__ float expo[NO_];
    __shared__ float s2sh[NO_];
    __shared__ float den;

    const int b = blockIdx.x, tid = threadIdx.x;
    const int o = tid >> 4, d = tid & 15;

    for (int f = tid; f < NI_ * DI_; f += 1024)
        xs[f] = X[(size_t)b * NI_ * DI_ + f];
    __syncthreads();

    float vprev = 0.f, v0 = 0.f, vout = 0.f;
    for (int phase = 0; phase < 3; ++phase) {
        float sacc = 0.f;
        for (int i = 0; i < NI_; ++i) {
            const float* wp = W + (size_t)i * 8192 + (size_t)tid * 8;
            const float* xp = xs + i * DI_;
            float u = 0.f;
#pragma unroll
            for (int k = 0; k < 8; ++k) u = fmaf(wp[k], xp[k], u);
            if (phase == 0) { sacc += u; continue; }
            if (d == 0) agree[o] = 0.f;
            __syncthreads();
            atomicAdd(&agree[o], u * vprev);
            __syncthreads();
            if (tid == 0) den = 0.f;
            __syncthreads();
            if (d == 0) { float e = __expf(agree[o]); expo[o] = e; atomicAdd(&den, e); }
            __syncthreads();
            float c = expo[o] / den;
            sacc = fmaf(c, u, sacc);
            if (phase == 2 && d == 0)
                outc[((size_t)b * NI_ + i) * NO_ + o] = c;
            __syncthreads();
        }
        if (phase == 0) sacc *= (1.0f / 64.0f);
        if (d == 0) s2sh[o] = 0.f;
        __syncthreads();
        atomicAdd(&s2sh[o], sacc * sacc);
        __syncthreads();
        const float s2 = s2sh[o];
        const float scale = s2 / ((1.0f + s2) * sqrtf(s2 + 1e-7f));
        const float vv = scale * sacc;
        if (phase == 0)      { v0 = vv; vprev = vv; }
        else if (phase == 1) { vprev = v0 + vv; }
        else                 { vout = vv; }
        __syncthreads();
    }
    outv[(size_t)b * (NO_ * DO_) + tid] = vout;
}

extern "C" void kernel_launch(void* const* d_in, const int* in_sizes, int n_in,
                              void* d_out, int out_size, void* d_ws, size_t ws_size,
                              hipStream_t stream)
{
    const float *X, *W;
    if (in_sizes[0] < in_sizes[1]) { X = (const float*)d_in[0]; W = (const float*)d_in[1]; }
    else                           { X = (const float*)d_in[1]; W = (const float*)d_in[0]; }

    float* out  = (float*)d_out;
    float* outv = out;             // v: [B,No,Do] fp32
    float* outc = out + V_ELEMS;   // c: [B,Ni,No] fp32

    const size_t needBig = ((size_t)B_ * CH_ * NOD_ + 2 * (size_t)B_ * NOD_) * sizeof(float);
    if (ws_size < needBig) {       // never expected (ws >= 64 MB measured R12)
        caps_naive<<<B_, 1024, 0, stream>>>(X, W, outv, outc);
        return;
    }

    float* part = (float*)d_ws;                      // 25.2 MB
    float* v0   = part + (size_t)B_ * CH_ * NOD_;
    float* w01  = v0 + (size_t)B_ * NOD_;

    dim3 gP(CH_, BSPLIT_), blk(256);
    caps_pass<0><<<gP, blk, 0, stream>>>(X, W, nullptr, part, nullptr);
    caps_squash<0><<<256, blk, 0, stream>>>(part, nullptr, v0, CH_);
    caps_pass<1><<<gP, blk, 0, stream>>>(X, W, v0, part, nullptr);
    caps_squash<1><<<256, blk, 0, stream>>>(part, v0, w01, CH_);
    caps_pass<2><<<gP, blk, 0, stream>>>(X, W, w01, part, outc);
    caps_squash<2><<<256, blk, 0, stream>>>(part, nullptr, outv, CH_);
}

// Round 15
// 229.653 us; speedup vs baseline: 4.3662x; 4.3662x over previous
//
#include <hip/hip_runtime.h>

// CapsNet dynamic routing — fp32 in / fp32 out (verified R11/R12).
// R14 lesson: lane=o mapping made every W load 64-line divergent and killed
// cross-b reuse (313 us/pass, VALU 8%). This round: R12's compute mapping
// (o=t>>2, q=t&3, 8 b's per block) + W[i] staged into LDS via fully
// coalesced dwordx4, compute reads via b128 from a +4-float padded tile
// (8 lanes per 4-bank group = structural optimum). v in registers.
// B=64, Ni=1152, Di=8, No=64, Do=16.
// u[b,i,o,d] = sum_k W[i*8192 + (o*16+d)*8 + k] * x[b*9216 + i*8 + k]
// it0: c=1/64       -> s0 -> v0
// it1: l=<u,v0>     -> c1 -> s1 -> v1
// it2: l=<u,v0+v1>  -> c2 (OUT [B,Ni,No]) -> s2 -> v2 (OUT [B,No,Do])

#define B_      64
#define NI_     1152
#define DI_     8
#define NO_     64
#define DO_     16
#define NOD_    1024
#define CH_     96
#define CI_     12
#define BG_     8
#define BSPLIT_ 8
#define V_ELEMS 65536
#define PADR    33      // float4 slots per o-row in LDS tile (132 floats)

static_assert(CH_ * CI_ == NI_, "chunking");
static_assert(BG_ * BSPLIT_ == B_, "b split");

// MODE 0: c=1/64 (applied in squash), acc sum_i u       -> part
// MODE 1: l=<u,v0>, softmax over o, acc c*u             -> part
// MODE 2: l=<u,v0+v1>, softmax, write c (fp32), acc c*u -> part
template <int MODE>
__global__ __launch_bounds__(256, 3)
void caps_pass(const float* __restrict__ X,
               const float* __restrict__ W,
               const float* __restrict__ vin,
               float* __restrict__ part,
               float* __restrict__ rw)
{
    __shared__ float  x_lds[BG_][CI_ * DI_];   // 3 KB
    __shared__ float4 wtile[NO_ * PADR];       // 33 KB padded W[i] tile
    __shared__ float  e_lds[BG_][NO_];         // 2 KB
    __shared__ float  invS[BG_];

    const int t  = threadIdx.x;
    const int o  = t >> 2, q = t & 3;
    const int ch = blockIdx.x;            // same-ch blocks 96 apart -> same XCD
    const int b0 = blockIdx.y * BG_;
    const int i0 = ch * CI_;

    // stage x[b0..b0+7][i0..i0+11][0..7]: 192 float4, coalesced
    for (int f = t; f < BG_ * CI_ * DI_ / 4; f += 256) {
        int bb = f / (CI_ * DI_ / 4), r = f - bb * (CI_ * DI_ / 4);
        ((float4*)x_lds)[f] =
            ((const float4*)(X + ((size_t)(b0 + bb) * NI_ + i0) * DI_))[r];
    }
    // routing vector -> registers: v[b][o*16 + q*4 + j]  (coalesced: addr = 4t)
    float vreg[BG_][4];
    if (MODE >= 1) {
#pragma unroll
        for (int b = 0; b < BG_; ++b) {
            float4 qv = *((const float4*)(vin + (size_t)(b0 + b) * NOD_ + 4 * t));
            vreg[b][0]=qv.x; vreg[b][1]=qv.y; vreg[b][2]=qv.z; vreg[b][3]=qv.w;
        }
    }
    __syncthreads();

    float acc[BG_][4];
#pragma unroll
    for (int b = 0; b < BG_; ++b) { acc[b][0]=0.f; acc[b][1]=0.f; acc[b][2]=0.f; acc[b][3]=0.f; }

    const float4* Wq = (const float4*)W;

    for (int ci = 0; ci < CI_; ++ci) {
        const int i = i0 + ci;

        // ---- stage W[i] (2048 float4 = 32 KB): 8 coalesced dwordx4/thread ----
        // Overwrite safety: all tile reads of iter ci-1 precede that iter's
        // barrier B/C, which every thread has passed before writing here.
        const float4* wg = Wq + (size_t)i * 2048;
        float4 tmp[8];
#pragma unroll
        for (int j = 0; j < 8; ++j) tmp[j] = wg[t + 256 * j];
#pragma unroll
        for (int j = 0; j < 8; ++j) {
            const int f = t + 256 * j;                    // linear float4 idx
            wtile[(f >> 5) * PADR + (f & 31)] = tmp[j];   // padded row
        }
        __syncthreads();   // A: tile ready

        // ---- wf = W[i][o][4q+jj][0..7] via 8 b128 reads (bank-optimal) ----
        float wf[4][8];
#pragma unroll
        for (int jj = 0; jj < 4; ++jj) {
            float4 a0 = wtile[o * PADR + (4 * q + jj) * 2];
            float4 a1 = wtile[o * PADR + (4 * q + jj) * 2 + 1];
            wf[jj][0]=a0.x; wf[jj][1]=a0.y; wf[jj][2]=a0.z; wf[jj][3]=a0.w;
            wf[jj][4]=a1.x; wf[jj][5]=a1.y; wf[jj][6]=a1.z; wf[jj][7]=a1.w;
        }

        float u[BG_][4];
#pragma unroll
        for (int b = 0; b < BG_; ++b) {
            const float* xb = &x_lds[b][ci * DI_];        // broadcast reads
            const float x0=xb[0],x1=xb[1],x2=xb[2],x3=xb[3];
            const float x4=xb[4],x5=xb[5],x6=xb[6],x7=xb[7];
#pragma unroll
            for (int jj = 0; jj < 4; ++jj) {
                float s = wf[jj][0] * x0;
                s = fmaf(wf[jj][1], x1, s); s = fmaf(wf[jj][2], x2, s);
                s = fmaf(wf[jj][3], x3, s); s = fmaf(wf[jj][4], x4, s);
                s = fmaf(wf[jj][5], x5, s); s = fmaf(wf[jj][6], x6, s);
                s = fmaf(wf[jj][7], x7, s);
                u[b][jj] = s;
            }
            if (MODE >= 1) {
                float a = u[b][0]*vreg[b][0] + u[b][1]*vreg[b][1]
                        + u[b][2]*vreg[b][2] + u[b][3]*vreg[b][3];
                a += __shfl_xor(a, 1);
                a += __shfl_xor(a, 2);          // full 16-d dot within quad
                if (q == 0) e_lds[b][o] = __expf(a);
            } else {
                acc[b][0]+=u[b][0]; acc[b][1]+=u[b][1];
                acc[b][2]+=u[b][2]; acc[b][3]+=u[b][3];
            }
        }

        if (MODE >= 1) {
            __syncthreads();   // B: e_lds complete (also fences tile reads)
            {
                const int bb = t >> 5, l = t & 31;
                float s = e_lds[bb][l] + e_lds[bb][l + 32];
                s += __shfl_xor(s, 1);  s += __shfl_xor(s, 2);  s += __shfl_xor(s, 4);
                s += __shfl_xor(s, 8);  s += __shfl_xor(s, 16);
                if (l == 0) invS[bb] = 1.0f / s;
            }
            __syncthreads();   // C: invS ready
#pragma unroll
            for (int b = 0; b < BG_; ++b) {
                const float c = e_lds[b][o] * invS[b];
                acc[b][0] = fmaf(c, u[b][0], acc[b][0]);
                acc[b][1] = fmaf(c, u[b][1], acc[b][1]);
                acc[b][2] = fmaf(c, u[b][2], acc[b][2]);
                acc[b][3] = fmaf(c, u[b][3], acc[b][3]);
                if (MODE == 2 && q == 0)
                    rw[((size_t)(b0 + b) * NI_ + i) * NO_ + o] = c;
            }
        } else {
            __syncthreads();   // MODE 0: fence tile reads before next overwrite
        }
    }

    // partial s: part[b][ch][4t..4t+3] (coalesced float4)
#pragma unroll
    for (int b = 0; b < BG_; ++b) {
        float4 val;
        val.x=acc[b][0]; val.y=acc[b][1]; val.z=acc[b][2]; val.w=acc[b][3];
        *((float4*)(part + (((size_t)(b0 + b) * CH_ + ch) * NOD_ + 4 * t))) = val;
    }
}

// Reduce partials over CH_ chunks (float4), squash over d, emit v.
// MODE 0: s*=1/64 -> v0 | MODE 1: w01 = v0 + squash(s1) | MODE 2: v2 -> d_out
template <int MODE>
__global__ __launch_bounds__(128)
void caps_squash(const float* __restrict__ part, const float* __restrict__ v0in,
                 float* __restrict__ vout)
{
    const int c4 = blockIdx.x * 128 + threadIdx.x;    // 0..16383: b*256 + o*4 + dq
    const int b = c4 >> 8, od4 = c4 & 255;
    const float4* p = (const float4*)part + (size_t)b * CH_ * 256 + od4;
    float4 s = {0.f, 0.f, 0.f, 0.f};
#pragma unroll 8
    for (int ch = 0; ch < CH_; ++ch) {
        float4 q = p[(size_t)ch * 256];
        s.x += q.x; s.y += q.y; s.z += q.z; s.w += q.w;
    }
    if (MODE == 0) { s.x*=(1.f/64.f); s.y*=(1.f/64.f); s.z*=(1.f/64.f); s.w*=(1.f/64.f); }
    float s2 = s.x*s.x + s.y*s.y + s.z*s.z + s.w*s.w;
    s2 += __shfl_xor(s2, 1); s2 += __shfl_xor(s2, 2);   // 4 dq-lanes = 16 d
    const float scale = s2 / ((1.0f + s2) * sqrtf(s2 + 1e-7f));
    float4 v; v.x = scale*s.x; v.y = scale*s.y; v.z = scale*s.z; v.w = scale*s.w;
    if (MODE == 1) {
        float4 v0 = ((const float4*)v0in)[c4];
        v.x += v0.x; v.y += v0.y; v.z += v0.z; v.w += v0.w;
    }
    ((float4*)vout)[c4] = v;
}

// Safety fallback (R11's passing kernel) — only if ws is unexpectedly tiny.
__global__ __launch_bounds__(1024, 1)
void caps_naive(const float* __restrict__ X, const float* __restrict__ W,
                float* __restrict__ outv, float* __restrict__ outc)
{
    __shared__ float xs[NI_ * DI_];
    __shared__ float agree[NO_];
    __shared__ float expo[NO_];
    __shared__ float s2sh[NO_];
    __shared__ float den;

    const int b = blockIdx.x, tid = threadIdx.x;
    const int o = tid >> 4, d = tid & 15;

    for (int f = tid; f < NI_ * DI_; f += 1024)
        xs[f] = X[(size_t)b * NI_ * DI_ + f];
    __syncthreads();

    float vprev = 0.f, v0 = 0.f, vout = 0.f;
    for (int phase = 0; phase < 3; ++phase) {
        float sacc = 0.f;
        for (int i = 0; i < NI_; ++i) {
            const float* wp = W + (size_t)i * 8192 + (size_t)tid * 8;
            const float* xp = xs + i * DI_;
            float u = 0.f;
#pragma unroll
            for (int k = 0; k < 8; ++k) u = fmaf(wp[k], xp[k], u);
            if (phase == 0) { sacc += u; continue; }
            if (d == 0) agree[o] = 0.f;
            __syncthreads();
            atomicAdd(&agree[o], u * vprev);
            __syncthreads();
            if (tid == 0) den = 0.f;
            __syncthreads();
            if (d == 0) { float e = __expf(agree[o]); expo[o] = e; atomicAdd(&den, e); }
            __syncthreads();
            float c = expo[o] / den;
            sacc = fmaf(c, u, sacc);
            if (phase == 2 && d == 0)
                outc[((size_t)b * NI_ + i) * NO_ + o] = c;
            __syncthreads();
        }
        if (phase == 0) sacc *= (1.0f / 64.0f);
        if (d == 0) s2sh[o] = 0.f;
        __syncthreads();
        atomicAdd(&s2sh[o], sacc * sacc);
        __syncthreads();
        const float s2 = s2sh[o];
        const float scale = s2 / ((1.0f + s2) * sqrtf(s2 + 1e-7f));
        const float vv = scale * sacc;
        if (phase == 0)      { v0 = vv; vprev = vv; }
        else if (phase == 1) { vprev = v0 + vv; }
        else                 { vout = vv; }
        __syncthreads();
    }
    outv[(size_t)b * (NO_ * DO_) + tid] = vout;
}

extern "C" void kernel_launch(void* const* d_in, const int* in_sizes, int n_in,
                              void* d_out, int out_size, void* d_ws, size_t ws_size,
                              hipStream_t stream)
{
    const float *X, *W;
    if (in_sizes[0] < in_sizes[1]) { X = (const float*)d_in[0]; W = (const float*)d_in[1]; }
    else                           { X = (const float*)d_in[1]; W = (const float*)d_in[0]; }

    float* out  = (float*)d_out;
    float* outv = out;             // v: [B,No,Do] fp32
    float* outc = out + V_ELEMS;   // c: [B,Ni,No] fp32

    const size_t needBig = ((size_t)B_ * CH_ * NOD_ + 2 * (size_t)B_ * NOD_) * sizeof(float);
    if (ws_size < needBig) {       // never expected (ws >= 64 MB measured R12)
        caps_naive<<<B_, 1024, 0, stream>>>(X, W, outv, outc);
        return;
    }

    float* part = (float*)d_ws;                      // 25.2 MB
    float* v0   = part + (size_t)B_ * CH_ * NOD_;
    float* w01  = v0 + (size_t)B_ * NOD_;

    dim3 gP(CH_, BSPLIT_), blk(256), gS(128), blkS(128);
    caps_pass<0><<<gP, blk, 0, stream>>>(X, W, nullptr, part, nullptr);
    caps_squash<0><<<gS, blkS, 0, stream>>>(part, nullptr, v0);
    caps_pass<1><<<gP, blk, 0, stream>>>(X, W, v0, part, nullptr);
    caps_squash<1><<<gS, blkS, 0, stream>>>(part, v0, w01);
    caps_pass<2><<<gP, blk, 0, stream>>>(X, W, w01, part, outc);
    caps_squash<2><<<gS, blkS, 0, stream>>>(part, nullptr, outv);
}